// Round 6
// baseline (198.655 us; speedup 1.0000x reference)
//
#include <hip/hip_runtime.h>

// C51 categorical projection. BS = 524288 rows x 51 atoms, fp32.
// Round 6: BRANCHLESS merge-scatter. R5 showed ~12 waves/CU with no pipe
// >30% busy and dur ~= 32 waves x ~5k cyc serial => near-zero cross-wave
// overlap; the merge loop's 51 divergent branches (v_cmp + s_and_saveexec +
// s_cbranch + exec restore, all on the shared SALU pipe) and the ~2000-instr
// unrolled body are the prime suspects.
//
// Trick: cur only moves forward and per-wave LDS ops are in-order, so we
// write the RUNNING accL to bin cur unconditionally every iteration -- the
// last write to each bin is its final value. State updates are 3 cndmask +
// 1 add: no branches, no exec-mask ops, no per-iter SALU.
//
// History: R1 stage+RMW scatter 71us; R2 LDS atomics 298us (never again);
// R3 direct global row reads 184us (204B-stride fragmentation); R4 merge+
// stage 77us (conflicts 8.1M->1.1M); R5 single-wave blocks 67us (barriers
// were not the bottleneck).

#define NUM_ATOMS 51
#define RPB 64
#define TILE (RPB * NUM_ATOMS)      // 3264 floats = 13056 B -> 12 blocks/CU
#define NV4 (TILE / 4)              // 816 float4 = 12*64 + 48

__global__ __launch_bounds__(RPB) void catproj_kernel(
    const float* __restrict__ reward,
    const float* __restrict__ probs,
    const float* __restrict__ not_done,
    float* __restrict__ out)
{
    __shared__ float lds[TILE];

    const int tid = threadIdx.x;               // 0..63 = lane
    const int row = blockIdx.x * RPB + tid;
    const int base = blockIdx.x * TILE;

    const float r  = reward[row];
    const float nd = not_done[row];

    // ---- Stage probs tile into LDS: flat coalesced b128 copy ----
    const float4* __restrict__ p4 = (const float4*)(probs + base);
    float4* __restrict__ l4 = (float4*)lds;
#pragma unroll
    for (int k = 0; k < 12; ++k) {
        const int i4 = k * RPB + tid;
        l4[i4] = p4[i4];
    }
    if (tid < NV4 - 12 * RPB)                  // remainder: 48 float4s
        l4[12 * RPB + tid] = p4[12 * RPB + tid];
    __syncthreads();                           // single wave: elided to waitcnt

    // ---- Read own contiguous row into registers (ds_read2 pairs) ----
    float* __restrict__ myrow = lds + tid * NUM_ATOMS;
    float p[NUM_ATOMS];
#pragma unroll
    for (int a = 0; a < NUM_ATOMS; ++a) p[a] = myrow[a];

    // Own row only from here (intra-wave, in-order LDS).
#pragma unroll
    for (int a = 0; a < NUM_ATOMS; ++a) myrow[a] = 0.0f;

    // ---- Branchless merge-scatter ----
    // b(a) = clamp(base2 + c*a, 0, 50), slope c <= 0.99 < 1 -> floor(b)
    // advances by 0 or 1 per atom. Unconditional write of running accL to
    // bin cur each iter; final write per bin wins (in-order per-wave LDS).
    const float c     = 0.99f * nd;
    const float base2 = fmaf(-25.f, c, fmaf(2.5f, r, 25.f)); // 2.5r+25-25c
    float curf = floorf(fminf(fmaxf(base2, 0.f), 50.f));     // lf(a=0)
    int   cur  = (int)curf;
    float accL = 0.f, accU = 0.f;
#pragma unroll
    for (int a = 0; a < NUM_ATOMS; ++a) {
        float b = fmaf(c, (float)a, base2);
        b = fminf(fmaxf(b, 0.f), 50.f);
        const float lf = floorf(b);
        const float pa = p[a];
        const float mu = (b - lf) * pa;   // upper mass (0 when b integral)
        const float ml = pa - mu;         // lower mass
        const bool adv = (lf != curf);    // v_cmp -> vcc, no branch
        accL = adv ? accU : accL;         // v_cndmask
        accU = adv ? 0.f : accU;          // v_cndmask
        cur += adv ? 1 : 0;               // v_addc-style
        curf = lf;                        // unconditional (lf==curf if !adv)
        accL += ml;
        accU += mu;
        myrow[cur] = accL;                // unconditional ds_write_b32
    }
    // Bin cur already holds its final accL (written in last iter).
    if (cur < NUM_ATOMS - 1) myrow[cur + 1] = accU;  // accU==0 when cur==50
    __syncthreads();                      // elided; ordering only

    // ---- Flat coalesced writeout ----
    const float4* __restrict__ s4 = (const float4*)lds;
    float4* __restrict__ o4 = (float4*)(out + base);
#pragma unroll
    for (int k = 0; k < 12; ++k) {
        const int i4 = k * RPB + tid;
        o4[i4] = s4[i4];
    }
    if (tid < NV4 - 12 * RPB)
        o4[12 * RPB + tid] = s4[12 * RPB + tid];
}

extern "C" void kernel_launch(void* const* d_in, const int* in_sizes, int n_in,
                              void* d_out, int out_size, void* d_ws, size_t ws_size,
                              hipStream_t stream) {
    const float* reward   = (const float*)d_in[0];
    const float* probs    = (const float*)d_in[1];
    const float* not_done = (const float*)d_in[2];
    float* out = (float*)d_out;

    const int bs = in_sizes[0];              // 524288
    const int grid = bs / RPB;               // 8192 blocks
    catproj_kernel<<<grid, RPB, 0, stream>>>(reward, probs, not_done, out);
}